// Round 31
// baseline (78.433 us; speedup 1.0000x reference)
//
#include <hip/hip_runtime.h>
#include <hip/hip_bf16.h>

#define B_ 8
#define T_ 2048
#define C_ 1024
#define H_ 128
#define M_ (B_ * T_)          // 16384 rows

typedef __bf16 bf16x8 __attribute__((ext_vector_type(8)));
typedef __bf16 bf16x4v __attribute__((ext_vector_type(4)));
typedef float f32x4 __attribute__((ext_vector_type(4)));

static __device__ __forceinline__ bf16x8 cvt8(float4 a, float4 b) {
    bf16x8 r;
    r[0] = (__bf16)a.x; r[1] = (__bf16)a.y; r[2] = (__bf16)a.z; r[3] = (__bf16)a.w;
    r[4] = (__bf16)b.x; r[5] = (__bf16)b.y; r[6] = (__bf16)b.z; r[7] = (__bf16)b.w;
    return r;
}

// ===========================================================================
// MAIN PATH
// ===========================================================================

__global__ __launch_bounds__(256) void wprep_kernel(
    const float* __restrict__ Wq, const float* __restrict__ Wk,
    const float* __restrict__ Wv, __bf16* __restrict__ wb)
{
    const int i = blockIdx.x * 256 + threadIdx.x;   // 0..98303 float4
    const int w = i >> 15;
    const int jj = i & 32767;
    const float* s = (w == 0) ? Wq : (w == 1) ? Wk : Wv;
    float4 v = ((const float4*)s)[jj];
    bf16x4v o;
    o[0] = (__bf16)v.x; o[1] = (__bf16)v.y; o[2] = (__bf16)v.z; o[3] = (__bf16)v.w;
    *(bf16x4v*)(wb + ((size_t)w << 17) + (size_t)jj * 4) = o;
}

// ---------------------------------------------------------------------------
// Fused projection GEMM: r26 structure with BK=128 (isolated A/B vs r30's
// BK=64; disambiguates r24's confounded regression). BM=64 x BN=128;
// As[64][128]=16KB + Bs[128][128]=32KB = 48KB -> 3 blocks/CU preserved.
// 8 k-steps (16 barrier exposures vs 32). XCD-coherent mapping unchanged.
// 16-slot swizzle (r19/r24-verified): write slot16 ^= row&15; reads use
// (kc*4+g4) ^ fr since row&15 == fr for all wave-tile rows.
// ---------------------------------------------------------------------------
__global__ __launch_bounds__(256) void proj_fused(
    const float* __restrict__ x, const __bf16* __restrict__ wb,
    __bf16* __restrict__ qb, __bf16* __restrict__ kb, __bf16* __restrict__ vTb)
{
    __shared__ __align__(16) __bf16 As[64 * 128];    // 16 KB
    __shared__ __align__(16) __bf16 Bs[128 * 128];   // 32 KB

    const int tid = threadIdx.x;
    const int lane = tid & 63;
    const int wid = tid >> 6;
    const int bx = blockIdx.x;          // 0..767
    const int base24 = bx / 24;         // 0..31
    const int rem24 = bx % 24;
    const int which = rem24 >> 3;       // 0..2  (same XCD for all 3)
    const int mt = base24 * 8 + (rem24 & 7);   // 0..255
    const int m0 = mt * 64;
    const int n0 = which * 128;         // row offset into wb

    const int wr = wid >> 1;            // 0..1 (32-row half)
    const int wc = wid & 1;             // 0..1 (64-col half)
    const int fr = lane & 15;
    const int g4 = lane >> 4;
    const int rbase = g4 * 4;

    f32x4 acc[2][4];
#pragma unroll
    for (int i = 0; i < 2; i++)
#pragma unroll
        for (int j = 0; j < 4; j++) acc[i][j] = (f32x4){0.f, 0.f, 0.f, 0.f};

    for (int kt = 0; kt < 8; kt++) {
        const int k0 = kt * 128;

        // --- stage A: 64 rows x 16 slots = 1024 chunks, 4/thread (reg cvt) ---
#pragma unroll
        for (int c = 0; c < 4; c++) {
            const int chunk = c * 256 + tid;
            const int arow = chunk >> 4;
            const int aslot = chunk & 15;
            const float* xs = x + (size_t)(m0 + arow) * C_ + k0 + aslot * 8;
            float4 xa = *(const float4*)xs;
            float4 xb2 = *(const float4*)(xs + 4);
            *(bf16x8*)&As[arow * 128 + ((aslot ^ (arow & 15)) << 3)] = cvt8(xa, xb2);
        }
        // --- stage B: 128 rows x 16 slots = 2048 chunks, 8/thread (glds) ---
#pragma unroll
        for (int i = 0; i < 8; i++) {
            const int chunk = i * 256 + tid;
            const int brow = chunk >> 4;
            const int bsrc = ((chunk & 15) ^ (brow & 15)) << 3;
            __builtin_amdgcn_global_load_lds(
                (const __attribute__((address_space(1))) void*)(wb + (size_t)(n0 + brow) * C_ + k0 + bsrc),
                (__attribute__((address_space(3))) void*)&Bs[chunk * 8], 16, 0, 0);
        }
        __syncthreads();

        // --- compute: 4 kc-chunks x 8 MFMA = 32 MFMA per wave ---
#pragma unroll
        for (int kc = 0; kc < 4; kc++) {
            const int sc = kc * 4 + g4;
            const int soff = (sc ^ fr) << 3;     // row&15 == fr for all rows
            bf16x8 ar[2], br[4];
#pragma unroll
            for (int i = 0; i < 2; i++)
                ar[i] = *(const bf16x8*)&As[(wr * 32 + i * 16 + fr) * 128 + soff];
#pragma unroll
            for (int j = 0; j < 4; j++)
                br[j] = *(const bf16x8*)&Bs[(wc * 64 + j * 16 + fr) * 128 + soff];
#pragma unroll
            for (int i = 0; i < 2; i++)
#pragma unroll
                for (int j = 0; j < 4; j++)
                    acc[i][j] = __builtin_amdgcn_mfma_f32_16x16x32_bf16(ar[i], br[j], acc[i][j], 0, 0, 0);
        }
        __syncthreads();
    }

    // Epilogue (which is block-uniform -> uniform branch).
#pragma unroll
    for (int i = 0; i < 2; i++) {
#pragma unroll
        for (int j = 0; j < 4; j++) {
            const int h = wc * 64 + j * 16 + fr;
#pragma unroll
            for (int rr = 0; rr < 4; rr++) {
                const int row = m0 + wr * 32 + i * 16 + rbase + rr;
                const __bf16 val = (__bf16)acc[i][j][rr];
                if (which == 0) {
                    qb[(size_t)row * H_ + h] = val;
                } else if (which == 1) {
                    kb[(size_t)row * H_ + h] = val;
                } else {
                    const int bb = row >> 11;
                    const int tt = row & (T_ - 1);
                    vTb[((size_t)bb * H_ + h) * T_ + tt] = val;
                }
            }
        }
    }
}

// ---------------------------------------------------------------------------
// 8-WAVE fused flash attention (r19-verified; F=1 split). Unchanged.
// ---------------------------------------------------------------------------
__global__ __launch_bounds__(512) void attn_fused(
    const __bf16* __restrict__ qb, const __bf16* __restrict__ kb,
    const __bf16* __restrict__ vTb,
    unsigned int* __restrict__ acc_ws, float* __restrict__ m_ws,
    float* __restrict__ l_ws)
{
    __shared__ __align__(16) __bf16 Klds[2][32 * 128];   // 2 x 8 KB
    __shared__ __align__(16) __bf16 Vlds[2][128 * 32];   // 2 x 8 KB
    __shared__ __align__(16) __bf16 pbuf[8][2][16][32];  // 16 KB (per-wave P)

    const int tid = threadIdx.x;
    const int lane = tid & 63;
    const int wid = tid >> 6;
    const int gw = blockIdx.x;          // 0..287
    const int b = gw & 7;               // XCD pin
    const int j = 35 - (gw >> 3);       // heavy-first
    int qc = 0;
#pragma unroll
    for (int q = 1; q < 8; q++) qc += (j >= (q * (q + 1)) / 2) ? 1 : 0;
    const int s = j - (qc * (qc + 1)) / 2;   // 0..qc
    const int lo = 8 * s, hi = 8 * s + 8;    // 8 tiles of 32 keys each

    const int qrow_loc = qc * 256 + wid * 32;        // batch-local first q-row
    const size_t qrow0 = (size_t)b * T_ + qrow_loc;

    const int fr = lane & 15;
    const int g4 = lane >> 4;
    const int koff = g4 * 8;
    const int rbase = g4 * 4;
    const int sw = fr & 6;

    const int krow = tid >> 4, kslot = tid & 15;     // K: 32 rows x 16 slots16
    const int vrow = tid >> 2, vslot = tid & 3;      // V: 128 rows x 4 slots16
    const __bf16* kgs = kb + ((size_t)b * T_ + krow) * H_ + ((kslot ^ (krow & 15)) << 3);
    const __bf16* vgs = vTb + ((size_t)b * H_ + vrow) * T_ + ((vslot ^ (vrow & 3)) << 3);

    bf16x8 qf[2][4];
#pragma unroll
    for (int g = 0; g < 2; g++) {
        const __bf16* Qb = qb + (qrow0 + g * 16 + fr) * H_ + koff;
#pragma unroll
        for (int hc = 0; hc < 4; hc++)
            qf[g][hc] = *(const bf16x8*)(Qb + hc * 32);
    }

    float m[2] = {-1e30f, -1e30f};
    float l[2] = {0.f, 0.f};
    f32x4 acc[2][8];
#pragma unroll
    for (int g = 0; g < 2; g++)
#pragma unroll
        for (int i = 0; i < 8; i++) acc[g][i] = (f32x4){0.f, 0.f, 0.f, 0.f};

    const float scale = 0.03125f;       // 1024^-0.5

    {
        const int k0 = lo * 32, nb = lo & 1;
        __builtin_amdgcn_global_load_lds(
            (const __attribute__((address_space(1))) void*)(kgs + (size_t)k0 * H_),
            (__attribute__((address_space(3))) void*)&Klds[nb][tid * 8], 16, 0, 0);
        __builtin_amdgcn_global_load_lds(
            (const __attribute__((address_space(1))) void*)(vgs + k0),
            (__attribute__((address_space(3))) void*)&Vlds[nb][tid * 8], 16, 0, 0);
    }

    for (int kt = lo; kt < hi; kt++) {
        const int k0 = kt * 32;
        const int pb = kt & 1;

        if (kt + 1 < hi) {
            const int k1 = (kt + 1) * 32, nb = (kt + 1) & 1;
            __builtin_amdgcn_global_load_lds(
                (const __attribute__((address_space(1))) void*)(kgs + (size_t)k1 * H_),
                (__attribute__((address_space(3))) void*)&Klds[nb][tid * 8], 16, 0, 0);
            __builtin_amdgcn_global_load_lds(
                (const __attribute__((address_space(1))) void*)(vgs + k1),
                (__attribute__((address_space(3))) void*)&Vlds[nb][tid * 8], 16, 0, 0);
        }
        __syncthreads();

        if (k0 <= qrow_loc + 31) {
            f32x4 sg[2][2];
#pragma unroll
            for (int g = 0; g < 2; g++) {
                sg[g][0] = (f32x4){0.f, 0.f, 0.f, 0.f};
                sg[g][1] = (f32x4){0.f, 0.f, 0.f, 0.f};
            }
            __builtin_amdgcn_s_setprio(1);
#pragma unroll
            for (int hc = 0; hc < 4; hc++) {
                const int r0 = fr, r1 = 16 + fr;
                bf16x8 kf0 = *(const bf16x8*)&Klds[pb][r0 * 128 + (((hc * 4 + g4) ^ (r0 & 15)) << 3)];
                bf16x8 kf1 = *(const bf16x8*)&Klds[pb][r1 * 128 + (((hc * 4 + g4) ^ (r1 & 15)) << 3)];
#pragma unroll
                for (int g = 0; g < 2; g++) {
                    sg[g][0] = __builtin_amdgcn_mfma_f32_16x16x32_bf16(kf0, qf[g][hc], sg[g][0], 0, 0, 0);
                    sg[g][1] = __builtin_amdgcn_mfma_f32_16x16x32_bf16(kf1, qf[g][hc], sg[g][1], 0, 0, 0);
                }
            }
            __builtin_amdgcn_s_setprio(0);

            float tv[2];
#pragma unroll
            for (int g = 0; g < 2; g++) {
                const int qrow = qrow_loc + g * 16 + fr;
                float t = -1e30f;
#pragma unroll
                for (int h = 0; h < 2; h++) {
#pragma unroll
                    for (int r = 0; r < 4; r++) {
                        const int key = k0 + h * 16 + rbase + r;
                        float v = sg[g][h][r] * scale;
                        v = (key > qrow) ? -1e30f : v;
                        sg[g][h][r] = v;
                        t = fmaxf(t, v);
                    }
                }
                t = fmaxf(t, __shfl_xor(t, 16));
                t = fmaxf(t, __shfl_xor(t, 32));
                tv[g] = t;
            }

            const bool need = (tv[0] > m[0] + 8.0f) || (tv[1] > m[1] + 8.0f);
            if (__any(need)) {
#pragma unroll
                for (int g = 0; g < 2; g++) {
                    const float mnew = fmaxf(m[g], tv[g]);
                    const float corr = __expf(m[g] - mnew);
                    l[g] *= corr;
#pragma unroll
                    for (int r = 0; r < 4; r++) {
                        const float cr = __shfl(corr, rbase + r);
#pragma unroll
                        for (int ht = 0; ht < 8; ht++) acc[g][ht][r] *= cr;
                    }
                    m[g] = mnew;
                }
            }

#pragma unroll
            for (int g = 0; g < 2; g++) {
                bf16x4v p0, p1;
                float sum = 0.f;
#pragma unroll
                for (int r = 0; r < 4; r++) {
                    const float e0 = __expf(sg[g][0][r] - m[g]);
                    const float e1 = __expf(sg[g][1][r] - m[g]);
                    p0[r] = (__bf16)e0;
                    p1[r] = (__bf16)e1;
                    sum += e0 + e1;
                }
                sum += __shfl_xor(sum, 16);
                sum += __shfl_xor(sum, 32);
                l[g] += sum;
                *(bf16x4v*)&pbuf[wid][g][fr][((g4) ^ sw) * 4] = p0;
                *(bf16x4v*)&pbuf[wid][g][fr][((4 + g4) ^ sw) * 4] = p1;
            }

            bf16x8 pa[2];
#pragma unroll
            for (int g = 0; g < 2; g++)
                pa[g] = *(const bf16x8*)&pbuf[wid][g][fr][((2 * g4) ^ sw) * 4];

            __builtin_amdgcn_s_setprio(1);
#pragma unroll
            for (int ht = 0; ht < 8; ht++) {
                const int vr = ht * 16 + fr;
                bf16x8 vf = *(const bf16x8*)&Vlds[pb][vr * 32 + ((g4 ^ (vr & 3)) << 3)];
#pragma unroll
                for (int g = 0; g < 2; g++)
                    acc[g][ht] = __builtin_amdgcn_mfma_f32_16x16x32_bf16(pa[g], vf, acc[g][ht], 0, 0, 0);
            }
            __builtin_amdgcn_s_setprio(0);
        }
        __syncthreads();
    }

#pragma unroll
    for (int g = 0; g < 2; g++) {
        const size_t row0 = qrow0 + g * 16;
#pragma unroll
        for (int p = 0; p < 4; p++) {
#pragma unroll
            for (int r = 0; r < 4; r++) {
                const __bf16 lo2 = (__bf16)acc[g][2 * p][r];
                const __bf16 hi2 = (__bf16)acc[g][2 * p + 1][r];
                const unsigned int w =
                    ((unsigned int)*(const unsigned short*)&hi2 << 16) |
                    *(const unsigned short*)&lo2;
                acc_ws[((size_t)s * M_ + row0 + rbase + r) * 64 + p * 16 + fr] = w;
            }
        }
    }

    if (lane < 16) {
#pragma unroll
        for (int g = 0; g < 2; g++) {
            const size_t row = qrow0 + g * 16 + lane;
            m_ws[(size_t)s * M_ + row] = m[g];
            l_ws[(size_t)s * M_ + row] = l[g];
        }
    }
}

// ---------------------------------------------------------------------------
// Merge: predicated full unroll over 8 slices (r28-verified). Unchanged.
// ---------------------------------------------------------------------------
__global__ __launch_bounds__(256) void attn_merge_bal(
    const unsigned int* __restrict__ acc_ws, const float* __restrict__ m_ws,
    const float* __restrict__ l_ws, float* __restrict__ out)
{
    const int lane = threadIdx.x & 63;
    const int g = blockIdx.x * 4 + (threadIdx.x >> 6);
    const int c = 1 + ((g >> 8) & 7);   // chunk qc = (row % 2048) / 256

    float ms[8], ls[8];
    unsigned int wv[8];
#pragma unroll
    for (int s = 0; s < 8; s++) {
        const bool v = (s < c);
        ms[s] = v ? m_ws[(size_t)s * M_ + g] : -1e30f;
        ls[s] = v ? l_ws[(size_t)s * M_ + g] : 0.f;
        wv[s] = v ? acc_ws[((size_t)s * M_ + g) * 64 + lane] : 0u;
    }

    float mm = -1e30f;
#pragma unroll
    for (int s = 0; s < 8; s++) mm = fmaxf(mm, ms[s]);
    float ll = 0.f, sc[8];
#pragma unroll
    for (int s = 0; s < 8; s++) {
        sc[s] = __expf(ms[s] - mm);
        ll += ls[s] * sc[s];
    }
    const float inv = 1.0f / ll;

    float ox = 0.f, oy = 0.f;
#pragma unroll
    for (int s = 0; s < 8; s++) {
        ox += __uint_as_float((wv[s] & 0xffffu) << 16) * sc[s];
        oy += __uint_as_float(wv[s] & 0xffff0000u) * sc[s];
    }
    ox *= inv; oy *= inv;
    const int col0 = ((lane >> 4) << 5) + (lane & 15);
    out[(size_t)g * H_ + col0] = ox;
    out[(size_t)g * H_ + col0 + 16] = oy;
}

// ===========================================================================
// FALLBACK PATH (round-4 verified; used only if ws_size too small)
// ===========================================================================
__global__ __launch_bounds__(64) void proj_kernel(
    const float* __restrict__ x,
    const float* __restrict__ Wq, const float* __restrict__ Wk,
    const float* __restrict__ Wv,
    __bf16* __restrict__ qb, __bf16* __restrict__ kb, __bf16* __restrict__ vTb)
{
    const int lane = threadIdx.x;
    const int gw = blockIdx.x;
    const int which = gw >> 10;
    const int mt = gw & 1023;
    const float* W = (which == 0) ? Wq : (which == 1) ? Wk : Wv;
    const int fr = lane & 15;
    const int koff = (lane >> 4) * 8;
    const float* xrow = x + (size_t)(mt * 16 + fr) * C_ + koff;
    const float* wbase = W + (size_t)fr * C_ + koff;
    f32x4 acc[8];
#pragma unroll
    for (int i = 0; i < 8; i++) acc[i] = (f32x4){0.f, 0.f, 0.f, 0.f};
    for (int kc = 0; kc < C_; kc += 32) {
        float4 xa = *(const float4*)(xrow + kc);
        float4 xb2 = *(const float4*)(xrow + kc + 4);
        bf16x8 af = cvt8(xa, xb2);
#pragma unroll
        for (int ht = 0; ht < 8; ht++) {
            const float* wrow = wbase + (size_t)ht * 16 * C_ + kc;
            float4 wa = *(const float4*)(wrow);
            float4 wb2 = *(const float4*)(wrow + 4);
            bf16x8 bfr = cvt8(wa, wb2);
            acc[ht] = __builtin_amdgcn_mfma_f32_16x16x32_bf16(af, bfr, acc[ht], 0, 0, 0);
        }
    }
    const int rbase = (lane >> 4) * 4;
#pragma unroll
    for (int ht = 0; ht < 8; ht++) {
#pragma unroll
        for (int r = 0; r < 4; r++) {
            int row = mt * 16 + rbase + r;
            int h = ht * 16 + fr;
            __bf16 val = (__bf16)acc[ht][r];
            if (which == 0) qb[(size_t)row * H_ + h] = val;
            else if (which == 1) kb[(size_t)row * H_ + h] = val;
            else {
                int bb = row >> 11; int tt = row & (T_ - 1);
                vTb[((size_t)bb * H_ + h) * T_ + tt] = val;
            }
        }
    }
}

__global__ __launch_bounds__(64) void attn_kernel(
    const __bf16* __restrict__ qb, const __bf16* __restrict__ kb,
    const __bf16* __restrict__ vTb, float* __restrict__ out)
{
    __shared__ __align__(16) __bf16 plds[16][32];
    const int lane = threadIdx.x;
    const int gw = blockIdx.x;
    const int b = gw >> 7;
    const int qt = gw & 127;
    const int q0 = qt * 16;
    const int fr = lane & 15;
    const int koff = (lane >> 4) * 8;
    const int rbase = (lane >> 4) * 4;
    const __bf16* Qbase = qb + ((size_t)b * T_ + q0 + fr) * H_ + koff;
    bf16x8 qf[4];
#pragma unroll
    for (int hc = 0; hc < 4; hc++) qf[hc] = *(const bf16x8*)(Qbase + hc * 32);
    float m[4], l[4];
    f32x4 acc[8];
#pragma unroll
    for (int r = 0; r < 4; r++) { m[r] = -1e30f; l[r] = 0.f; }
#pragma unroll
    for (int i = 0; i < 8; i++) acc[i] = (f32x4){0.f, 0.f, 0.f, 0.f};
    const int nkt = (q0 + 15) / 32 + 1;
    const float scale = 0.03125f;
    for (int kt = 0; kt < nkt; kt++) {
        const int k0 = kt * 32;
        f32x4 s0 = (f32x4){0.f, 0.f, 0.f, 0.f};
        f32x4 s1 = (f32x4){0.f, 0.f, 0.f, 0.f};
        const __bf16* Kb0 = kb + ((size_t)b * T_ + k0 + fr) * H_ + koff;
        const __bf16* Kb1 = Kb0 + 16 * H_;
#pragma unroll
        for (int hc = 0; hc < 4; hc++) {
            bf16x8 kf0 = *(const bf16x8*)(Kb0 + hc * 32);
            s0 = __builtin_amdgcn_mfma_f32_16x16x32_bf16(qf[hc], kf0, s0, 0, 0, 0);
            bf16x8 kf1 = *(const bf16x8*)(Kb1 + hc * 32);
            s1 = __builtin_amdgcn_mfma_f32_16x16x32_bf16(qf[hc], kf1, s1, 0, 0, 0);
        }
#pragma unroll
        for (int r = 0; r < 4; r++) {
            const int qrow = q0 + rbase + r;
            float v0 = s0[r] * scale;
            float v1 = s1[r] * scale;
            if (k0 + fr > qrow)      v0 = -1e30f;
            if (k0 + 16 + fr > qrow) v1 = -1e30f;
            float mx = fmaxf(v0, v1);
#pragma unroll
            for (int d = 1; d < 16; d <<= 1) mx = fmaxf(mx, __shfl_xor(mx, d));
            const float mnew = fmaxf(m[r], mx);
            const float corr = __expf(m[r] - mnew);
            const float e0 = __expf(v0 - mnew);
            const float e1 = __expf(v1 - mnew);
            float rs = e0 + e1;
#pragma unroll
            for (int d = 1; d < 16; d <<= 1) rs += __shfl_xor(rs, d);
            l[r] = l[r] * corr + rs;
            m[r] = mnew;
#pragma unroll
            for (int ht = 0; ht < 8; ht++) acc[ht][r] *= corr;
            plds[rbase + r][fr] = (__bf16)e0;
            plds[rbase + r][16 + fr] = (__bf16)e1;
        }
        __syncthreads();
        bf16x8 pa = *(const bf16x8*)(&plds[fr][koff]);
        const __bf16* Vb = vTb + ((size_t)b * H_ + fr) * T_ + k0 + koff;
#pragma unroll
        for (int ht = 0; ht < 8; ht++) {
            bf16x8 vf = *(const bf16x8*)(Vb + (size_t)ht * 16 * T_);
            acc[ht] = __builtin_amdgcn_mfma_f32_16x16x32_bf16(pa, vf, acc[ht], 0, 0, 0);
        }
        __syncthreads();
    }
    float inv[4];
#pragma unroll
    for (int r = 0; r < 4; r++) inv[r] = 1.0f / l[r];
    float* obase = out + ((size_t)b * T_ + q0 + rbase) * H_ + fr;
#pragma unroll
    for (int ht = 0; ht < 8; ht++) {
#pragma unroll
        for (int r = 0; r < 4; r++) {
            obase[(size_t)r * H_ + ht * 16] = acc[ht][r] * inv[r];
        }
    }
}

// ===========================================================================
extern "C" void kernel_launch(void* const* d_in, const int* in_sizes, int n_in,
                              void* d_out, int out_size, void* d_ws, size_t ws_size,
                              hipStream_t stream) {
    const float* x  = (const float*)d_in[0];
    const float* Wk = (const float*)d_in[1];
    const float* Wq = (const float*)d_in[2];
    const float* Wv = (const float*)d_in[3];
    float* out = (float*)d_out;
    uint8_t* ws = (uint8_t*)d_ws;

    // Workspace: acc (bf16-packed, 8 slices) 33,554,432 | wb 786,432 |
    //            qb/kb/vTb 3x4,194,304 | m_ws 524,288 | l_ws 524,288
    const size_t NEED = 47972352;

    if (ws_size >= NEED) {
        unsigned int* acc_ws = (unsigned int*)ws;
        __bf16* wb  = (__bf16*)(ws + 33554432);
        __bf16* qb  = (__bf16*)(ws + 34340864);
        __bf16* kb  = (__bf16*)(ws + 38535168);
        __bf16* vTb = (__bf16*)(ws + 42729472);
        float*  m_ws = (float*)(ws + 46923776);
        float*  l_ws = (float*)(ws + 47448064);

        wprep_kernel<<<384, 256, 0, stream>>>(Wq, Wk, Wv, wb);
        proj_fused<<<768, 256, 0, stream>>>(x, wb, qb, kb, vTb);
        attn_fused<<<B_ * 36, 512, 0, stream>>>(qb, kb, vTb, acc_ws, m_ws, l_ws);
        attn_merge_bal<<<M_ / 4, 256, 0, stream>>>(acc_ws, m_ws, l_ws, out);
    } else {
        // Fallback: round-4 verified path (needs 12.6 MB)
        __bf16* qb  = (__bf16*)d_ws;
        __bf16* kb  = qb + (size_t)M_ * H_;
        __bf16* vTb = kb + (size_t)M_ * H_;
        proj_kernel<<<3072, 64, 0, stream>>>(x, Wq, Wk, Wv, qb, kb, vTb);
        attn_kernel<<<1024, 64, 0, stream>>>(qb, kb, vTb, out);
    }
}

// Round 32
// 78.003 us; speedup vs baseline: 1.0055x; 1.0055x over previous
//
#include <hip/hip_runtime.h>
#include <hip/hip_bf16.h>

#define B_ 8
#define T_ 2048
#define C_ 1024
#define H_ 128
#define M_ (B_ * T_)          // 16384 rows

typedef __bf16 bf16x8 __attribute__((ext_vector_type(8)));
typedef __bf16 bf16x4v __attribute__((ext_vector_type(4)));
typedef float f32x4 __attribute__((ext_vector_type(4)));

static __device__ __forceinline__ bf16x8 cvt8(float4 a, float4 b) {
    bf16x8 r;
    r[0] = (__bf16)a.x; r[1] = (__bf16)a.y; r[2] = (__bf16)a.z; r[3] = (__bf16)a.w;
    r[4] = (__bf16)b.x; r[5] = (__bf16)b.y; r[6] = (__bf16)b.z; r[7] = (__bf16)b.w;
    return r;
}

// ===========================================================================
// MAIN PATH
// ===========================================================================

__global__ __launch_bounds__(256) void wprep_kernel(
    const float* __restrict__ Wq, const float* __restrict__ Wk,
    const float* __restrict__ Wv, __bf16* __restrict__ wb)
{
    const int i = blockIdx.x * 256 + threadIdx.x;   // 0..98303 float4
    const int w = i >> 15;
    const int jj = i & 32767;
    const float* s = (w == 0) ? Wq : (w == 1) ? Wk : Wv;
    float4 v = ((const float4*)s)[jj];
    bf16x4v o;
    o[0] = (__bf16)v.x; o[1] = (__bf16)v.y; o[2] = (__bf16)v.z; o[3] = (__bf16)v.w;
    *(bf16x4v*)(wb + ((size_t)w << 17) + (size_t)jj * 4) = o;
}

// ---------------------------------------------------------------------------
// Fused projection GEMM: BK=128 (r31: proj 39.2-40.0 us, verified faster
// than r30's BK=64 at 42.5-46.4). BM=64 x BN=128; As 16KB + Bs 32KB = 48KB
// -> 3 blocks/CU. 8 k-steps. XCD-coherent mapping. 16-slot swizzle.
// This round: byte-identical resubmission (reproducibility A/B on the
// total; r31 total 78.4 vs r30 76.6 despite faster proj).
// ---------------------------------------------------------------------------
__global__ __launch_bounds__(256) void proj_fused(
    const float* __restrict__ x, const __bf16* __restrict__ wb,
    __bf16* __restrict__ qb, __bf16* __restrict__ kb, __bf16* __restrict__ vTb)
{
    __shared__ __align__(16) __bf16 As[64 * 128];    // 16 KB
    __shared__ __align__(16) __bf16 Bs[128 * 128];   // 32 KB

    const int tid = threadIdx.x;
    const int lane = tid & 63;
    const int wid = tid >> 6;
    const int bx = blockIdx.x;          // 0..767
    const int base24 = bx / 24;         // 0..31
    const int rem24 = bx % 24;
    const int which = rem24 >> 3;       // 0..2  (same XCD for all 3)
    const int mt = base24 * 8 + (rem24 & 7);   // 0..255
    const int m0 = mt * 64;
    const int n0 = which * 128;         // row offset into wb

    const int wr = wid >> 1;            // 0..1 (32-row half)
    const int wc = wid & 1;             // 0..1 (64-col half)
    const int fr = lane & 15;
    const int g4 = lane >> 4;
    const int rbase = g4 * 4;

    f32x4 acc[2][4];
#pragma unroll
    for (int i = 0; i < 2; i++)
#pragma unroll
        for (int j = 0; j < 4; j++) acc[i][j] = (f32x4){0.f, 0.f, 0.f, 0.f};

    for (int kt = 0; kt < 8; kt++) {
        const int k0 = kt * 128;

        // --- stage A: 64 rows x 16 slots = 1024 chunks, 4/thread (reg cvt) ---
#pragma unroll
        for (int c = 0; c < 4; c++) {
            const int chunk = c * 256 + tid;
            const int arow = chunk >> 4;
            const int aslot = chunk & 15;
            const float* xs = x + (size_t)(m0 + arow) * C_ + k0 + aslot * 8;
            float4 xa = *(const float4*)xs;
            float4 xb2 = *(const float4*)(xs + 4);
            *(bf16x8*)&As[arow * 128 + ((aslot ^ (arow & 15)) << 3)] = cvt8(xa, xb2);
        }
        // --- stage B: 128 rows x 16 slots = 2048 chunks, 8/thread (glds) ---
#pragma unroll
        for (int i = 0; i < 8; i++) {
            const int chunk = i * 256 + tid;
            const int brow = chunk >> 4;
            const int bsrc = ((chunk & 15) ^ (brow & 15)) << 3;
            __builtin_amdgcn_global_load_lds(
                (const __attribute__((address_space(1))) void*)(wb + (size_t)(n0 + brow) * C_ + k0 + bsrc),
                (__attribute__((address_space(3))) void*)&Bs[chunk * 8], 16, 0, 0);
        }
        __syncthreads();

        // --- compute: 4 kc-chunks x 8 MFMA = 32 MFMA per wave ---
#pragma unroll
        for (int kc = 0; kc < 4; kc++) {
            const int sc = kc * 4 + g4;
            const int soff = (sc ^ fr) << 3;     // row&15 == fr for all rows
            bf16x8 ar[2], br[4];
#pragma unroll
            for (int i = 0; i < 2; i++)
                ar[i] = *(const bf16x8*)&As[(wr * 32 + i * 16 + fr) * 128 + soff];
#pragma unroll
            for (int j = 0; j < 4; j++)
                br[j] = *(const bf16x8*)&Bs[(wc * 64 + j * 16 + fr) * 128 + soff];
#pragma unroll
            for (int i = 0; i < 2; i++)
#pragma unroll
                for (int j = 0; j < 4; j++)
                    acc[i][j] = __builtin_amdgcn_mfma_f32_16x16x32_bf16(ar[i], br[j], acc[i][j], 0, 0, 0);
        }
        __syncthreads();
    }

    // Epilogue (which is block-uniform -> uniform branch).
#pragma unroll
    for (int i = 0; i < 2; i++) {
#pragma unroll
        for (int j = 0; j < 4; j++) {
            const int h = wc * 64 + j * 16 + fr;
#pragma unroll
            for (int rr = 0; rr < 4; rr++) {
                const int row = m0 + wr * 32 + i * 16 + rbase + rr;
                const __bf16 val = (__bf16)acc[i][j][rr];
                if (which == 0) {
                    qb[(size_t)row * H_ + h] = val;
                } else if (which == 1) {
                    kb[(size_t)row * H_ + h] = val;
                } else {
                    const int bb = row >> 11;
                    const int tt = row & (T_ - 1);
                    vTb[((size_t)bb * H_ + h) * T_ + tt] = val;
                }
            }
        }
    }
}

// ---------------------------------------------------------------------------
// 8-WAVE fused flash attention (r19-verified; F=1 split). Unchanged.
// ---------------------------------------------------------------------------
__global__ __launch_bounds__(512) void attn_fused(
    const __bf16* __restrict__ qb, const __bf16* __restrict__ kb,
    const __bf16* __restrict__ vTb,
    unsigned int* __restrict__ acc_ws, float* __restrict__ m_ws,
    float* __restrict__ l_ws)
{
    __shared__ __align__(16) __bf16 Klds[2][32 * 128];   // 2 x 8 KB
    __shared__ __align__(16) __bf16 Vlds[2][128 * 32];   // 2 x 8 KB
    __shared__ __align__(16) __bf16 pbuf[8][2][16][32];  // 16 KB (per-wave P)

    const int tid = threadIdx.x;
    const int lane = tid & 63;
    const int wid = tid >> 6;
    const int gw = blockIdx.x;          // 0..287
    const int b = gw & 7;               // XCD pin
    const int j = 35 - (gw >> 3);       // heavy-first
    int qc = 0;
#pragma unroll
    for (int q = 1; q < 8; q++) qc += (j >= (q * (q + 1)) / 2) ? 1 : 0;
    const int s = j - (qc * (qc + 1)) / 2;   // 0..qc
    const int lo = 8 * s, hi = 8 * s + 8;    // 8 tiles of 32 keys each

    const int qrow_loc = qc * 256 + wid * 32;        // batch-local first q-row
    const size_t qrow0 = (size_t)b * T_ + qrow_loc;

    const int fr = lane & 15;
    const int g4 = lane >> 4;
    const int koff = g4 * 8;
    const int rbase = g4 * 4;
    const int sw = fr & 6;

    const int krow = tid >> 4, kslot = tid & 15;     // K: 32 rows x 16 slots16
    const int vrow = tid >> 2, vslot = tid & 3;      // V: 128 rows x 4 slots16
    const __bf16* kgs = kb + ((size_t)b * T_ + krow) * H_ + ((kslot ^ (krow & 15)) << 3);
    const __bf16* vgs = vTb + ((size_t)b * H_ + vrow) * T_ + ((vslot ^ (vrow & 3)) << 3);

    bf16x8 qf[2][4];
#pragma unroll
    for (int g = 0; g < 2; g++) {
        const __bf16* Qb = qb + (qrow0 + g * 16 + fr) * H_ + koff;
#pragma unroll
        for (int hc = 0; hc < 4; hc++)
            qf[g][hc] = *(const bf16x8*)(Qb + hc * 32);
    }

    float m[2] = {-1e30f, -1e30f};
    float l[2] = {0.f, 0.f};
    f32x4 acc[2][8];
#pragma unroll
    for (int g = 0; g < 2; g++)
#pragma unroll
        for (int i = 0; i < 8; i++) acc[g][i] = (f32x4){0.f, 0.f, 0.f, 0.f};

    const float scale = 0.03125f;       // 1024^-0.5

    {
        const int k0 = lo * 32, nb = lo & 1;
        __builtin_amdgcn_global_load_lds(
            (const __attribute__((address_space(1))) void*)(kgs + (size_t)k0 * H_),
            (__attribute__((address_space(3))) void*)&Klds[nb][tid * 8], 16, 0, 0);
        __builtin_amdgcn_global_load_lds(
            (const __attribute__((address_space(1))) void*)(vgs + k0),
            (__attribute__((address_space(3))) void*)&Vlds[nb][tid * 8], 16, 0, 0);
    }

    for (int kt = lo; kt < hi; kt++) {
        const int k0 = kt * 32;
        const int pb = kt & 1;

        if (kt + 1 < hi) {
            const int k1 = (kt + 1) * 32, nb = (kt + 1) & 1;
            __builtin_amdgcn_global_load_lds(
                (const __attribute__((address_space(1))) void*)(kgs + (size_t)k1 * H_),
                (__attribute__((address_space(3))) void*)&Klds[nb][tid * 8], 16, 0, 0);
            __builtin_amdgcn_global_load_lds(
                (const __attribute__((address_space(1))) void*)(vgs + k1),
                (__attribute__((address_space(3))) void*)&Vlds[nb][tid * 8], 16, 0, 0);
        }
        __syncthreads();

        if (k0 <= qrow_loc + 31) {
            f32x4 sg[2][2];
#pragma unroll
            for (int g = 0; g < 2; g++) {
                sg[g][0] = (f32x4){0.f, 0.f, 0.f, 0.f};
                sg[g][1] = (f32x4){0.f, 0.f, 0.f, 0.f};
            }
            __builtin_amdgcn_s_setprio(1);
#pragma unroll
            for (int hc = 0; hc < 4; hc++) {
                const int r0 = fr, r1 = 16 + fr;
                bf16x8 kf0 = *(const bf16x8*)&Klds[pb][r0 * 128 + (((hc * 4 + g4) ^ (r0 & 15)) << 3)];
                bf16x8 kf1 = *(const bf16x8*)&Klds[pb][r1 * 128 + (((hc * 4 + g4) ^ (r1 & 15)) << 3)];
#pragma unroll
                for (int g = 0; g < 2; g++) {
                    sg[g][0] = __builtin_amdgcn_mfma_f32_16x16x32_bf16(kf0, qf[g][hc], sg[g][0], 0, 0, 0);
                    sg[g][1] = __builtin_amdgcn_mfma_f32_16x16x32_bf16(kf1, qf[g][hc], sg[g][1], 0, 0, 0);
                }
            }
            __builtin_amdgcn_s_setprio(0);

            float tv[2];
#pragma unroll
            for (int g = 0; g < 2; g++) {
                const int qrow = qrow_loc + g * 16 + fr;
                float t = -1e30f;
#pragma unroll
                for (int h = 0; h < 2; h++) {
#pragma unroll
                    for (int r = 0; r < 4; r++) {
                        const int key = k0 + h * 16 + rbase + r;
                        float v = sg[g][h][r] * scale;
                        v = (key > qrow) ? -1e30f : v;
                        sg[g][h][r] = v;
                        t = fmaxf(t, v);
                    }
                }
                t = fmaxf(t, __shfl_xor(t, 16));
                t = fmaxf(t, __shfl_xor(t, 32));
                tv[g] = t;
            }

            const bool need = (tv[0] > m[0] + 8.0f) || (tv[1] > m[1] + 8.0f);
            if (__any(need)) {
#pragma unroll
                for (int g = 0; g < 2; g++) {
                    const float mnew = fmaxf(m[g], tv[g]);
                    const float corr = __expf(m[g] - mnew);
                    l[g] *= corr;
#pragma unroll
                    for (int r = 0; r < 4; r++) {
                        const float cr = __shfl(corr, rbase + r);
#pragma unroll
                        for (int ht = 0; ht < 8; ht++) acc[g][ht][r] *= cr;
                    }
                    m[g] = mnew;
                }
            }

#pragma unroll
            for (int g = 0; g < 2; g++) {
                bf16x4v p0, p1;
                float sum = 0.f;
#pragma unroll
                for (int r = 0; r < 4; r++) {
                    const float e0 = __expf(sg[g][0][r] - m[g]);
                    const float e1 = __expf(sg[g][1][r] - m[g]);
                    p0[r] = (__bf16)e0;
                    p1[r] = (__bf16)e1;
                    sum += e0 + e1;
                }
                sum += __shfl_xor(sum, 16);
                sum += __shfl_xor(sum, 32);
                l[g] += sum;
                *(bf16x4v*)&pbuf[wid][g][fr][((g4) ^ sw) * 4] = p0;
                *(bf16x4v*)&pbuf[wid][g][fr][((4 + g4) ^ sw) * 4] = p1;
            }

            bf16x8 pa[2];
#pragma unroll
            for (int g = 0; g < 2; g++)
                pa[g] = *(const bf16x8*)&pbuf[wid][g][fr][((2 * g4) ^ sw) * 4];

            __builtin_amdgcn_s_setprio(1);
#pragma unroll
            for (int ht = 0; ht < 8; ht++) {
                const int vr = ht * 16 + fr;
                bf16x8 vf = *(const bf16x8*)&Vlds[pb][vr * 32 + ((g4 ^ (vr & 3)) << 3)];
#pragma unroll
                for (int g = 0; g < 2; g++)
                    acc[g][ht] = __builtin_amdgcn_mfma_f32_16x16x32_bf16(pa[g], vf, acc[g][ht], 0, 0, 0);
            }
            __builtin_amdgcn_s_setprio(0);
        }
        __syncthreads();
    }

#pragma unroll
    for (int g = 0; g < 2; g++) {
        const size_t row0 = qrow0 + g * 16;
#pragma unroll
        for (int p = 0; p < 4; p++) {
#pragma unroll
            for (int r = 0; r < 4; r++) {
                const __bf16 lo2 = (__bf16)acc[g][2 * p][r];
                const __bf16 hi2 = (__bf16)acc[g][2 * p + 1][r];
                const unsigned int w =
                    ((unsigned int)*(const unsigned short*)&hi2 << 16) |
                    *(const unsigned short*)&lo2;
                acc_ws[((size_t)s * M_ + row0 + rbase + r) * 64 + p * 16 + fr] = w;
            }
        }
    }

    if (lane < 16) {
#pragma unroll
        for (int g = 0; g < 2; g++) {
            const size_t row = qrow0 + g * 16 + lane;
            m_ws[(size_t)s * M_ + row] = m[g];
            l_ws[(size_t)s * M_ + row] = l[g];
        }
    }
}

// ---------------------------------------------------------------------------
// Merge: predicated full unroll over 8 slices (r28-verified). Unchanged.
// ---------------------------------------------------------------------------
__global__ __launch_bounds__(256) void attn_merge_bal(
    const unsigned int* __restrict__ acc_ws, const float* __restrict__ m_ws,
    const float* __restrict__ l_ws, float* __restrict__ out)
{
    const int lane = threadIdx.x & 63;
    const int g = blockIdx.x * 4 + (threadIdx.x >> 6);
    const int c = 1 + ((g >> 8) & 7);   // chunk qc = (row % 2048) / 256

    float ms[8], ls[8];
    unsigned int wv[8];
#pragma unroll
    for (int s = 0; s < 8; s++) {
        const bool v = (s < c);
        ms[s] = v ? m_ws[(size_t)s * M_ + g] : -1e30f;
        ls[s] = v ? l_ws[(size_t)s * M_ + g] : 0.f;
        wv[s] = v ? acc_ws[((size_t)s * M_ + g) * 64 + lane] : 0u;
    }

    float mm = -1e30f;
#pragma unroll
    for (int s = 0; s < 8; s++) mm = fmaxf(mm, ms[s]);
    float ll = 0.f, sc[8];
#pragma unroll
    for (int s = 0; s < 8; s++) {
        sc[s] = __expf(ms[s] - mm);
        ll += ls[s] * sc[s];
    }
    const float inv = 1.0f / ll;

    float ox = 0.f, oy = 0.f;
#pragma unroll
    for (int s = 0; s < 8; s++) {
        ox += __uint_as_float((wv[s] & 0xffffu) << 16) * sc[s];
        oy += __uint_as_float(wv[s] & 0xffff0000u) * sc[s];
    }
    ox *= inv; oy *= inv;
    const int col0 = ((lane >> 4) << 5) + (lane & 15);
    out[(size_t)g * H_ + col0] = ox;
    out[(size_t)g * H_ + col0 + 16] = oy;
}

// ===========================================================================
// FALLBACK PATH (round-4 verified; used only if ws_size too small)
// ===========================================================================
__global__ __launch_bounds__(64) void proj_kernel(
    const float* __restrict__ x,
    const float* __restrict__ Wq, const float* __restrict__ Wk,
    const float* __restrict__ Wv,
    __bf16* __restrict__ qb, __bf16* __restrict__ kb, __bf16* __restrict__ vTb)
{
    const int lane = threadIdx.x;
    const int gw = blockIdx.x;
    const int which = gw >> 10;
    const int mt = gw & 1023;
    const float* W = (which == 0) ? Wq : (which == 1) ? Wk : Wv;
    const int fr = lane & 15;
    const int koff = (lane >> 4) * 8;
    const float* xrow = x + (size_t)(mt * 16 + fr) * C_ + koff;
    const float* wbase = W + (size_t)fr * C_ + koff;
    f32x4 acc[8];
#pragma unroll
    for (int i = 0; i < 8; i++) acc[i] = (f32x4){0.f, 0.f, 0.f, 0.f};
    for (int kc = 0; kc < C_; kc += 32) {
        float4 xa = *(const float4*)(xrow + kc);
        float4 xb2 = *(const float4*)(xrow + kc + 4);
        bf16x8 af = cvt8(xa, xb2);
#pragma unroll
        for (int ht = 0; ht < 8; ht++) {
            const float* wrow = wbase + (size_t)ht * 16 * C_ + kc;
            float4 wa = *(const float4*)(wrow);
            float4 wb2 = *(const float4*)(wrow + 4);
            bf16x8 bfr = cvt8(wa, wb2);
            acc[ht] = __builtin_amdgcn_mfma_f32_16x16x32_bf16(af, bfr, acc[ht], 0, 0, 0);
        }
    }
    const int rbase = (lane >> 4) * 4;
#pragma unroll
    for (int ht = 0; ht < 8; ht++) {
#pragma unroll
        for (int r = 0; r < 4; r++) {
            int row = mt * 16 + rbase + r;
            int h = ht * 16 + fr;
            __bf16 val = (__bf16)acc[ht][r];
            if (which == 0) qb[(size_t)row * H_ + h] = val;
            else if (which == 1) kb[(size_t)row * H_ + h] = val;
            else {
                int bb = row >> 11; int tt = row & (T_ - 1);
                vTb[((size_t)bb * H_ + h) * T_ + tt] = val;
            }
        }
    }
}

__global__ __launch_bounds__(64) void attn_kernel(
    const __bf16* __restrict__ qb, const __bf16* __restrict__ kb,
    const __bf16* __restrict__ vTb, float* __restrict__ out)
{
    __shared__ __align__(16) __bf16 plds[16][32];
    const int lane = threadIdx.x;
    const int gw = blockIdx.x;
    const int b = gw >> 7;
    const int qt = gw & 127;
    const int q0 = qt * 16;
    const int fr = lane & 15;
    const int koff = (lane >> 4) * 8;
    const int rbase = (lane >> 4) * 4;
    const __bf16* Qbase = qb + ((size_t)b * T_ + q0 + fr) * H_ + koff;
    bf16x8 qf[4];
#pragma unroll
    for (int hc = 0; hc < 4; hc++) qf[hc] = *(const bf16x8*)(Qbase + hc * 32);
    float m[4], l[4];
    f32x4 acc[8];
#pragma unroll
    for (int r = 0; r < 4; r++) { m[r] = -1e30f; l[r] = 0.f; }
#pragma unroll
    for (int i = 0; i < 8; i++) acc[i] = (f32x4){0.f, 0.f, 0.f, 0.f};
    const int nkt = (q0 + 15) / 32 + 1;
    const float scale = 0.03125f;
    for (int kt = 0; kt < nkt; kt++) {
        const int k0 = kt * 32;
        f32x4 s0 = (f32x4){0.f, 0.f, 0.f, 0.f};
        f32x4 s1 = (f32x4){0.f, 0.f, 0.f, 0.f};
        const __bf16* Kb0 = kb + ((size_t)b * T_ + k0 + fr) * H_ + koff;
        const __bf16* Kb1 = Kb0 + 16 * H_;
#pragma unroll
        for (int hc = 0; hc < 4; hc++) {
            bf16x8 kf0 = *(const bf16x8*)(Kb0 + hc * 32);
            s0 = __builtin_amdgcn_mfma_f32_16x16x32_bf16(qf[hc], kf0, s0, 0, 0, 0);
            bf16x8 kf1 = *(const bf16x8*)(Kb1 + hc * 32);
            s1 = __builtin_amdgcn_mfma_f32_16x16x32_bf16(qf[hc], kf1, s1, 0, 0, 0);
        }
#pragma unroll
        for (int r = 0; r < 4; r++) {
            const int qrow = q0 + rbase + r;
            float v0 = s0[r] * scale;
            float v1 = s1[r] * scale;
            if (k0 + fr > qrow)      v0 = -1e30f;
            if (k0 + 16 + fr > qrow) v1 = -1e30f;
            float mx = fmaxf(v0, v1);
#pragma unroll
            for (int d = 1; d < 16; d <<= 1) mx = fmaxf(mx, __shfl_xor(mx, d));
            const float mnew = fmaxf(m[r], mx);
            const float corr = __expf(m[r] - mnew);
            const float e0 = __expf(v0 - mnew);
            const float e1 = __expf(v1 - mnew);
            float rs = e0 + e1;
#pragma unroll
            for (int d = 1; d < 16; d <<= 1) rs += __shfl_xor(rs, d);
            l[r] = l[r] * corr + rs;
            m[r] = mnew;
#pragma unroll
            for (int ht = 0; ht < 8; ht++) acc[ht][r] *= corr;
            plds[rbase + r][fr] = (__bf16)e0;
            plds[rbase + r][16 + fr] = (__bf16)e1;
        }
        __syncthreads();
        bf16x8 pa = *(const bf16x8*)(&plds[fr][koff]);
        const __bf16* Vb = vTb + ((size_t)b * H_ + fr) * T_ + k0 + koff;
#pragma unroll
        for (int ht = 0; ht < 8; ht++) {
            bf16x8 vf = *(const bf16x8*)(Vb + (size_t)ht * 16 * T_);
            acc[ht] = __builtin_amdgcn_mfma_f32_16x16x32_bf16(pa, vf, acc[ht], 0, 0, 0);
        }
        __syncthreads();
    }
    float inv[4];
#pragma unroll
    for (int r = 0; r < 4; r++) inv[r] = 1.0f / l[r];
    float* obase = out + ((size_t)b * T_ + q0 + rbase) * H_ + fr;
#pragma unroll
    for (int ht = 0; ht < 8; ht++) {
#pragma unroll
        for (int r = 0; r < 4; r++) {
            obase[(size_t)r * H_ + ht * 16] = acc[ht][r] * inv[r];
        }
    }
}

// ===========================================================================
extern "C" void kernel_launch(void* const* d_in, const int* in_sizes, int n_in,
                              void* d_out, int out_size, void* d_ws, size_t ws_size,
                              hipStream_t stream) {
    const float* x  = (const float*)d_in[0];
    const float* Wk = (const float*)d_in[1];
    const float* Wq = (const float*)d_in[2];
    const float* Wv = (const float*)d_in[3];
    float* out = (float*)d_out;
    uint8_t* ws = (uint8_t*)d_ws;

    // Workspace: acc (bf16-packed, 8 slices) 33,554,432 | wb 786,432 |
    //            qb/kb/vTb 3x4,194,304 | m_ws 524,288 | l_ws 524,288
    const size_t NEED = 47972352;

    if (ws_size >= NEED) {
        unsigned int* acc_ws = (unsigned int*)ws;
        __bf16* wb  = (__bf16*)(ws + 33554432);
        __bf16* qb  = (__bf16*)(ws + 34340864);
        __bf16* kb  = (__bf16*)(ws + 38535168);
        __bf16* vTb = (__bf16*)(ws + 42729472);
        float*  m_ws = (float*)(ws + 46923776);
        float*  l_ws = (float*)(ws + 47448064);

        wprep_kernel<<<384, 256, 0, stream>>>(Wq, Wk, Wv, wb);
        proj_fused<<<768, 256, 0, stream>>>(x, wb, qb, kb, vTb);
        attn_fused<<<B_ * 36, 512, 0, stream>>>(qb, kb, vTb, acc_ws, m_ws, l_ws);
        attn_merge_bal<<<M_ / 4, 256, 0, stream>>>(acc_ws, m_ws, l_ws, out);
    } else {
        // Fallback: round-4 verified path (needs 12.6 MB)
        __bf16* qb  = (__bf16*)d_ws;
        __bf16* kb  = qb + (size_t)M_ * H_;
        __bf16* vTb = kb + (size_t)M_ * H_;
        proj_kernel<<<3072, 64, 0, stream>>>(x, Wq, Wk, Wv, qb, kb, vTb);
        attn_kernel<<<1024, 64, 0, stream>>>(qb, kb, vTb, out);
    }
}

// Round 33
// 76.281 us; speedup vs baseline: 1.0282x; 1.0226x over previous
//
#include <hip/hip_runtime.h>
#include <hip/hip_bf16.h>

#define B_ 8
#define T_ 2048
#define C_ 1024
#define H_ 128
#define M_ (B_ * T_)          // 16384 rows

typedef __bf16 bf16x8 __attribute__((ext_vector_type(8)));
typedef __bf16 bf16x4v __attribute__((ext_vector_type(4)));
typedef float f32x4 __attribute__((ext_vector_type(4)));

static __device__ __forceinline__ bf16x8 cvt8(float4 a, float4 b) {
    bf16x8 r;
    r[0] = (__bf16)a.x; r[1] = (__bf16)a.y; r[2] = (__bf16)a.z; r[3] = (__bf16)a.w;
    r[4] = (__bf16)b.x; r[5] = (__bf16)b.y; r[6] = (__bf16)b.z; r[7] = (__bf16)b.w;
    return r;
}

// ===========================================================================
// MAIN PATH (r28-exact: best measured total 76.6 us, verified twice)
// ===========================================================================

__global__ __launch_bounds__(256) void wprep_kernel(
    const float* __restrict__ Wq, const float* __restrict__ Wk,
    const float* __restrict__ Wv, __bf16* __restrict__ wb)
{
    const int i = blockIdx.x * 256 + threadIdx.x;   // 0..98303 float4
    const int w = i >> 15;
    const int jj = i & 32767;
    const float* s = (w == 0) ? Wq : (w == 1) ? Wk : Wv;
    float4 v = ((const float4*)s)[jj];
    bf16x4v o;
    o[0] = (__bf16)v.x; o[1] = (__bf16)v.y; o[2] = (__bf16)v.z; o[3] = (__bf16)v.w;
    *(bf16x4v*)(wb + ((size_t)w << 17) + (size_t)jj * 4) = o;
}

// ---------------------------------------------------------------------------
// Fused projection GEMM: BM=64 x BN=128, grid 768 = 3 blocks/CU, 24 KB LDS.
// BK=64 (BK=128 made proj faster but perturbed co-compiled attn codegen for
// a net total loss — rule #19, confirmed by r31/r32 A/B). XCD-coherent
// mapping (FETCH 37 MB verified), XOR swizzle (conflicts=0 verified).
// ---------------------------------------------------------------------------
__global__ __launch_bounds__(256) void proj_fused(
    const float* __restrict__ x, const __bf16* __restrict__ wb,
    __bf16* __restrict__ qb, __bf16* __restrict__ kb, __bf16* __restrict__ vTb)
{
    __shared__ __align__(16) __bf16 As[64 * 64];     // 8 KB
    __shared__ __align__(16) __bf16 Bs[128 * 64];    // 16 KB

    const int tid = threadIdx.x;
    const int lane = tid & 63;
    const int wid = tid >> 6;
    const int bx = blockIdx.x;          // 0..767
    const int base24 = bx / 24;         // 0..31
    const int rem24 = bx % 24;
    const int which = rem24 >> 3;       // 0..2  (same XCD for all 3)
    const int mt = base24 * 8 + (rem24 & 7);   // 0..255
    const int m0 = mt * 64;
    const int n0 = which * 128;         // row offset into wb

    const int wr = wid >> 1;
    const int wc = wid & 1;
    const int fr = lane & 15;
    const int g4 = lane >> 4;
    const int rbase = g4 * 4;
    const int sw8 = fr & 7;

    f32x4 acc[2][4];
#pragma unroll
    for (int i = 0; i < 2; i++)
#pragma unroll
        for (int j = 0; j < 4; j++) acc[i][j] = (f32x4){0.f, 0.f, 0.f, 0.f};

    for (int kt = 0; kt < 16; kt++) {
        const int k0 = kt * 64;

#pragma unroll
        for (int c = 0; c < 2; c++) {
            const int chunk = c * 256 + tid;
            const int arow = chunk >> 3;
            const int aslot = chunk & 7;
            const float* xs = x + (size_t)(m0 + arow) * C_ + k0 + aslot * 8;
            float4 xa = *(const float4*)xs;
            float4 xb2 = *(const float4*)(xs + 4);
            *(bf16x8*)&As[arow * 64 + ((aslot ^ (arow & 7)) << 3)] = cvt8(xa, xb2);
        }
#pragma unroll
        for (int i = 0; i < 4; i++) {
            const int chunk = i * 256 + tid;
            const int brow = chunk >> 3;
            const int bsrc = ((chunk & 7) ^ (brow & 7)) << 3;
            __builtin_amdgcn_global_load_lds(
                (const __attribute__((address_space(1))) void*)(wb + (size_t)(n0 + brow) * C_ + k0 + bsrc),
                (__attribute__((address_space(3))) void*)&Bs[chunk * 8], 16, 0, 0);
        }
        __syncthreads();

#pragma unroll
        for (int kk = 0; kk < 2; kk++) {
            const int sc = kk * 4 + g4;
            const int soff = (sc ^ sw8) << 3;
            bf16x8 ar[2], br[4];
#pragma unroll
            for (int i = 0; i < 2; i++)
                ar[i] = *(const bf16x8*)&As[(wr * 32 + i * 16 + fr) * 64 + soff];
#pragma unroll
            for (int j = 0; j < 4; j++)
                br[j] = *(const bf16x8*)&Bs[(wc * 64 + j * 16 + fr) * 64 + soff];
#pragma unroll
            for (int i = 0; i < 2; i++)
#pragma unroll
                for (int j = 0; j < 4; j++)
                    acc[i][j] = __builtin_amdgcn_mfma_f32_16x16x32_bf16(ar[i], br[j], acc[i][j], 0, 0, 0);
        }
        __syncthreads();
    }

#pragma unroll
    for (int i = 0; i < 2; i++) {
#pragma unroll
        for (int j = 0; j < 4; j++) {
            const int h = wc * 64 + j * 16 + fr;
#pragma unroll
            for (int rr = 0; rr < 4; rr++) {
                const int row = m0 + wr * 32 + i * 16 + rbase + rr;
                const __bf16 val = (__bf16)acc[i][j][rr];
                if (which == 0) {
                    qb[(size_t)row * H_ + h] = val;
                } else if (which == 1) {
                    kb[(size_t)row * H_ + h] = val;
                } else {
                    const int bb = row >> 11;
                    const int tt = row & (T_ - 1);
                    vTb[((size_t)bb * H_ + h) * T_ + tt] = val;
                }
            }
        }
    }
}

// ---------------------------------------------------------------------------
// 8-WAVE fused flash attention (r19-verified; F=1 split: 288 blocks).
// ---------------------------------------------------------------------------
__global__ __launch_bounds__(512) void attn_fused(
    const __bf16* __restrict__ qb, const __bf16* __restrict__ kb,
    const __bf16* __restrict__ vTb,
    unsigned int* __restrict__ acc_ws, float* __restrict__ m_ws,
    float* __restrict__ l_ws)
{
    __shared__ __align__(16) __bf16 Klds[2][32 * 128];   // 2 x 8 KB
    __shared__ __align__(16) __bf16 Vlds[2][128 * 32];   // 2 x 8 KB
    __shared__ __align__(16) __bf16 pbuf[8][2][16][32];  // 16 KB (per-wave P)

    const int tid = threadIdx.x;
    const int lane = tid & 63;
    const int wid = tid >> 6;
    const int gw = blockIdx.x;          // 0..287
    const int b = gw & 7;               // XCD pin
    const int j = 35 - (gw >> 3);       // heavy-first
    int qc = 0;
#pragma unroll
    for (int q = 1; q < 8; q++) qc += (j >= (q * (q + 1)) / 2) ? 1 : 0;
    const int s = j - (qc * (qc + 1)) / 2;   // 0..qc
    const int lo = 8 * s, hi = 8 * s + 8;    // 8 tiles of 32 keys each

    const int qrow_loc = qc * 256 + wid * 32;        // batch-local first q-row
    const size_t qrow0 = (size_t)b * T_ + qrow_loc;

    const int fr = lane & 15;
    const int g4 = lane >> 4;
    const int koff = g4 * 8;
    const int rbase = g4 * 4;
    const int sw = fr & 6;

    const int krow = tid >> 4, kslot = tid & 15;     // K: 32 rows x 16 slots16
    const int vrow = tid >> 2, vslot = tid & 3;      // V: 128 rows x 4 slots16
    const __bf16* kgs = kb + ((size_t)b * T_ + krow) * H_ + ((kslot ^ (krow & 15)) << 3);
    const __bf16* vgs = vTb + ((size_t)b * H_ + vrow) * T_ + ((vslot ^ (vrow & 3)) << 3);

    bf16x8 qf[2][4];
#pragma unroll
    for (int g = 0; g < 2; g++) {
        const __bf16* Qb = qb + (qrow0 + g * 16 + fr) * H_ + koff;
#pragma unroll
        for (int hc = 0; hc < 4; hc++)
            qf[g][hc] = *(const bf16x8*)(Qb + hc * 32);
    }

    float m[2] = {-1e30f, -1e30f};
    float l[2] = {0.f, 0.f};
    f32x4 acc[2][8];
#pragma unroll
    for (int g = 0; g < 2; g++)
#pragma unroll
        for (int i = 0; i < 8; i++) acc[g][i] = (f32x4){0.f, 0.f, 0.f, 0.f};

    const float scale = 0.03125f;       // 1024^-0.5

    {
        const int k0 = lo * 32, nb = lo & 1;
        __builtin_amdgcn_global_load_lds(
            (const __attribute__((address_space(1))) void*)(kgs + (size_t)k0 * H_),
            (__attribute__((address_space(3))) void*)&Klds[nb][tid * 8], 16, 0, 0);
        __builtin_amdgcn_global_load_lds(
            (const __attribute__((address_space(1))) void*)(vgs + k0),
            (__attribute__((address_space(3))) void*)&Vlds[nb][tid * 8], 16, 0, 0);
    }

    for (int kt = lo; kt < hi; kt++) {
        const int k0 = kt * 32;
        const int pb = kt & 1;

        if (kt + 1 < hi) {
            const int k1 = (kt + 1) * 32, nb = (kt + 1) & 1;
            __builtin_amdgcn_global_load_lds(
                (const __attribute__((address_space(1))) void*)(kgs + (size_t)k1 * H_),
                (__attribute__((address_space(3))) void*)&Klds[nb][tid * 8], 16, 0, 0);
            __builtin_amdgcn_global_load_lds(
                (const __attribute__((address_space(1))) void*)(vgs + k1),
                (__attribute__((address_space(3))) void*)&Vlds[nb][tid * 8], 16, 0, 0);
        }
        __syncthreads();

        if (k0 <= qrow_loc + 31) {
            f32x4 sg[2][2];
#pragma unroll
            for (int g = 0; g < 2; g++) {
                sg[g][0] = (f32x4){0.f, 0.f, 0.f, 0.f};
                sg[g][1] = (f32x4){0.f, 0.f, 0.f, 0.f};
            }
            __builtin_amdgcn_s_setprio(1);
#pragma unroll
            for (int hc = 0; hc < 4; hc++) {
                const int r0 = fr, r1 = 16 + fr;
                bf16x8 kf0 = *(const bf16x8*)&Klds[pb][r0 * 128 + (((hc * 4 + g4) ^ (r0 & 15)) << 3)];
                bf16x8 kf1 = *(const bf16x8*)&Klds[pb][r1 * 128 + (((hc * 4 + g4) ^ (r1 & 15)) << 3)];
#pragma unroll
                for (int g = 0; g < 2; g++) {
                    sg[g][0] = __builtin_amdgcn_mfma_f32_16x16x32_bf16(kf0, qf[g][hc], sg[g][0], 0, 0, 0);
                    sg[g][1] = __builtin_amdgcn_mfma_f32_16x16x32_bf16(kf1, qf[g][hc], sg[g][1], 0, 0, 0);
                }
            }
            __builtin_amdgcn_s_setprio(0);

            float tv[2];
#pragma unroll
            for (int g = 0; g < 2; g++) {
                const int qrow = qrow_loc + g * 16 + fr;
                float t = -1e30f;
#pragma unroll
                for (int h = 0; h < 2; h++) {
#pragma unroll
                    for (int r = 0; r < 4; r++) {
                        const int key = k0 + h * 16 + rbase + r;
                        float v = sg[g][h][r] * scale;
                        v = (key > qrow) ? -1e30f : v;
                        sg[g][h][r] = v;
                        t = fmaxf(t, v);
                    }
                }
                t = fmaxf(t, __shfl_xor(t, 16));
                t = fmaxf(t, __shfl_xor(t, 32));
                tv[g] = t;
            }

            const bool need = (tv[0] > m[0] + 8.0f) || (tv[1] > m[1] + 8.0f);
            if (__any(need)) {
#pragma unroll
                for (int g = 0; g < 2; g++) {
                    const float mnew = fmaxf(m[g], tv[g]);
                    const float corr = __expf(m[g] - mnew);
                    l[g] *= corr;
#pragma unroll
                    for (int r = 0; r < 4; r++) {
                        const float cr = __shfl(corr, rbase + r);
#pragma unroll
                        for (int ht = 0; ht < 8; ht++) acc[g][ht][r] *= cr;
                    }
                    m[g] = mnew;
                }
            }

#pragma unroll
            for (int g = 0; g < 2; g++) {
                bf16x4v p0, p1;
                float sum = 0.f;
#pragma unroll
                for (int r = 0; r < 4; r++) {
                    const float e0 = __expf(sg[g][0][r] - m[g]);
                    const float e1 = __expf(sg[g][1][r] - m[g]);
                    p0[r] = (__bf16)e0;
                    p1[r] = (__bf16)e1;
                    sum += e0 + e1;
                }
                sum += __shfl_xor(sum, 16);
                sum += __shfl_xor(sum, 32);
                l[g] += sum;
                *(bf16x4v*)&pbuf[wid][g][fr][((g4) ^ sw) * 4] = p0;
                *(bf16x4v*)&pbuf[wid][g][fr][((4 + g4) ^ sw) * 4] = p1;
            }

            bf16x8 pa[2];
#pragma unroll
            for (int g = 0; g < 2; g++)
                pa[g] = *(const bf16x8*)&pbuf[wid][g][fr][((2 * g4) ^ sw) * 4];

            __builtin_amdgcn_s_setprio(1);
#pragma unroll
            for (int ht = 0; ht < 8; ht++) {
                const int vr = ht * 16 + fr;
                bf16x8 vf = *(const bf16x8*)&Vlds[pb][vr * 32 + ((g4 ^ (vr & 3)) << 3)];
#pragma unroll
                for (int g = 0; g < 2; g++)
                    acc[g][ht] = __builtin_amdgcn_mfma_f32_16x16x32_bf16(pa[g], vf, acc[g][ht], 0, 0, 0);
            }
            __builtin_amdgcn_s_setprio(0);
        }
        __syncthreads();
    }

#pragma unroll
    for (int g = 0; g < 2; g++) {
        const size_t row0 = qrow0 + g * 16;
#pragma unroll
        for (int p = 0; p < 4; p++) {
#pragma unroll
            for (int r = 0; r < 4; r++) {
                const __bf16 lo2 = (__bf16)acc[g][2 * p][r];
                const __bf16 hi2 = (__bf16)acc[g][2 * p + 1][r];
                const unsigned int w =
                    ((unsigned int)*(const unsigned short*)&hi2 << 16) |
                    *(const unsigned short*)&lo2;
                acc_ws[((size_t)s * M_ + row0 + rbase + r) * 64 + p * 16 + fr] = w;
            }
        }
    }

    if (lane < 16) {
#pragma unroll
        for (int g = 0; g < 2; g++) {
            const size_t row = qrow0 + g * 16 + lane;
            m_ws[(size_t)s * M_ + row] = m[g];
            l_ws[(size_t)s * M_ + row] = l[g];
        }
    }
}

// ---------------------------------------------------------------------------
// Merge: predicated full unroll over 8 slices (r28-verified).
// ---------------------------------------------------------------------------
__global__ __launch_bounds__(256) void attn_merge_bal(
    const unsigned int* __restrict__ acc_ws, const float* __restrict__ m_ws,
    const float* __restrict__ l_ws, float* __restrict__ out)
{
    const int lane = threadIdx.x & 63;
    const int g = blockIdx.x * 4 + (threadIdx.x >> 6);
    const int c = 1 + ((g >> 8) & 7);   // chunk qc = (row % 2048) / 256

    float ms[8], ls[8];
    unsigned int wv[8];
#pragma unroll
    for (int s = 0; s < 8; s++) {
        const bool v = (s < c);
        ms[s] = v ? m_ws[(size_t)s * M_ + g] : -1e30f;
        ls[s] = v ? l_ws[(size_t)s * M_ + g] : 0.f;
        wv[s] = v ? acc_ws[((size_t)s * M_ + g) * 64 + lane] : 0u;
    }

    float mm = -1e30f;
#pragma unroll
    for (int s = 0; s < 8; s++) mm = fmaxf(mm, ms[s]);
    float ll = 0.f, sc[8];
#pragma unroll
    for (int s = 0; s < 8; s++) {
        sc[s] = __expf(ms[s] - mm);
        ll += ls[s] * sc[s];
    }
    const float inv = 1.0f / ll;

    float ox = 0.f, oy = 0.f;
#pragma unroll
    for (int s = 0; s < 8; s++) {
        ox += __uint_as_float((wv[s] & 0xffffu) << 16) * sc[s];
        oy += __uint_as_float(wv[s] & 0xffff0000u) * sc[s];
    }
    ox *= inv; oy *= inv;
    const int col0 = ((lane >> 4) << 5) + (lane & 15);
    out[(size_t)g * H_ + col0] = ox;
    out[(size_t)g * H_ + col0 + 16] = oy;
}

// ===========================================================================
// FALLBACK PATH (round-4 verified; used only if ws_size too small)
// ===========================================================================
__global__ __launch_bounds__(64) void proj_kernel(
    const float* __restrict__ x,
    const float* __restrict__ Wq, const float* __restrict__ Wk,
    const float* __restrict__ Wv,
    __bf16* __restrict__ qb, __bf16* __restrict__ kb, __bf16* __restrict__ vTb)
{
    const int lane = threadIdx.x;
    const int gw = blockIdx.x;
    const int which = gw >> 10;
    const int mt = gw & 1023;
    const float* W = (which == 0) ? Wq : (which == 1) ? Wk : Wv;
    const int fr = lane & 15;
    const int koff = (lane >> 4) * 8;
    const float* xrow = x + (size_t)(mt * 16 + fr) * C_ + koff;
    const float* wbase = W + (size_t)fr * C_ + koff;
    f32x4 acc[8];
#pragma unroll
    for (int i = 0; i < 8; i++) acc[i] = (f32x4){0.f, 0.f, 0.f, 0.f};
    for (int kc = 0; kc < C_; kc += 32) {
        float4 xa = *(const float4*)(xrow + kc);
        float4 xb2 = *(const float4*)(xrow + kc + 4);
        bf16x8 af = cvt8(xa, xb2);
#pragma unroll
        for (int ht = 0; ht < 8; ht++) {
            const float* wrow = wbase + (size_t)ht * 16 * C_ + kc;
            float4 wa = *(const float4*)(wrow);
            float4 wb2 = *(const float4*)(wrow + 4);
            bf16x8 bfr = cvt8(wa, wb2);
            acc[ht] = __builtin_amdgcn_mfma_f32_16x16x32_bf16(af, bfr, acc[ht], 0, 0, 0);
        }
    }
    const int rbase = (lane >> 4) * 4;
#pragma unroll
    for (int ht = 0; ht < 8; ht++) {
#pragma unroll
        for (int r = 0; r < 4; r++) {
            int row = mt * 16 + rbase + r;
            int h = ht * 16 + fr;
            __bf16 val = (__bf16)acc[ht][r];
            if (which == 0) qb[(size_t)row * H_ + h] = val;
            else if (which == 1) kb[(size_t)row * H_ + h] = val;
            else {
                int bb = row >> 11; int tt = row & (T_ - 1);
                vTb[((size_t)bb * H_ + h) * T_ + tt] = val;
            }
        }
    }
}

__global__ __launch_bounds__(64) void attn_kernel(
    const __bf16* __restrict__ qb, const __bf16* __restrict__ kb,
    const __bf16* __restrict__ vTb, float* __restrict__ out)
{
    __shared__ __align__(16) __bf16 plds[16][32];
    const int lane = threadIdx.x;
    const int gw = blockIdx.x;
    const int b = gw >> 7;
    const int qt = gw & 127;
    const int q0 = qt * 16;
    const int fr = lane & 15;
    const int koff = (lane >> 4) * 8;
    const int rbase = (lane >> 4) * 4;
    const __bf16* Qbase = qb + ((size_t)b * T_ + q0 + fr) * H_ + koff;
    bf16x8 qf[4];
#pragma unroll
    for (int hc = 0; hc < 4; hc++) qf[hc] = *(const bf16x8*)(Qbase + hc * 32);
    float m[4], l[4];
    f32x4 acc[8];
#pragma unroll
    for (int r = 0; r < 4; r++) { m[r] = -1e30f; l[r] = 0.f; }
#pragma unroll
    for (int i = 0; i < 8; i++) acc[i] = (f32x4){0.f, 0.f, 0.f, 0.f};
    const int nkt = (q0 + 15) / 32 + 1;
    const float scale = 0.03125f;
    for (int kt = 0; kt < nkt; kt++) {
        const int k0 = kt * 32;
        f32x4 s0 = (f32x4){0.f, 0.f, 0.f, 0.f};
        f32x4 s1 = (f32x4){0.f, 0.f, 0.f, 0.f};
        const __bf16* Kb0 = kb + ((size_t)b * T_ + k0 + fr) * H_ + koff;
        const __bf16* Kb1 = Kb0 + 16 * H_;
#pragma unroll
        for (int hc = 0; hc < 4; hc++) {
            bf16x8 kf0 = *(const bf16x8*)(Kb0 + hc * 32);
            s0 = __builtin_amdgcn_mfma_f32_16x16x32_bf16(qf[hc], kf0, s0, 0, 0, 0);
            bf16x8 kf1 = *(const bf16x8*)(Kb1 + hc * 32);
            s1 = __builtin_amdgcn_mfma_f32_16x16x32_bf16(qf[hc], kf1, s1, 0, 0, 0);
        }
#pragma unroll
        for (int r = 0; r < 4; r++) {
            const int qrow = q0 + rbase + r;
            float v0 = s0[r] * scale;
            float v1 = s1[r] * scale;
            if (k0 + fr > qrow)      v0 = -1e30f;
            if (k0 + 16 + fr > qrow) v1 = -1e30f;
            float mx = fmaxf(v0, v1);
#pragma unroll
            for (int d = 1; d < 16; d <<= 1) mx = fmaxf(mx, __shfl_xor(mx, d));
            const float mnew = fmaxf(m[r], mx);
            const float corr = __expf(m[r] - mnew);
            const float e0 = __expf(v0 - mnew);
            const float e1 = __expf(v1 - mnew);
            float rs = e0 + e1;
#pragma unroll
            for (int d = 1; d < 16; d <<= 1) rs += __shfl_xor(rs, d);
            l[r] = l[r] * corr + rs;
            m[r] = mnew;
#pragma unroll
            for (int ht = 0; ht < 8; ht++) acc[ht][r] *= corr;
            plds[rbase + r][fr] = (__bf16)e0;
            plds[rbase + r][16 + fr] = (__bf16)e1;
        }
        __syncthreads();
        bf16x8 pa = *(const bf16x8*)(&plds[fr][koff]);
        const __bf16* Vb = vTb + ((size_t)b * H_ + fr) * T_ + k0 + koff;
#pragma unroll
        for (int ht = 0; ht < 8; ht++) {
            bf16x8 vf = *(const bf16x8*)(Vb + (size_t)ht * 16 * T_);
            acc[ht] = __builtin_amdgcn_mfma_f32_16x16x32_bf16(pa, vf, acc[ht], 0, 0, 0);
        }
        __syncthreads();
    }
    float inv[4];
#pragma unroll
    for (int r = 0; r < 4; r++) inv[r] = 1.0f / l[r];
    float* obase = out + ((size_t)b * T_ + q0 + rbase) * H_ + fr;
#pragma unroll
    for (int ht = 0; ht < 8; ht++) {
#pragma unroll
        for (int r = 0; r < 4; r++) {
            obase[(size_t)r * H_ + ht * 16] = acc[ht][r] * inv[r];
        }
    }
}

// ===========================================================================
extern "C" void kernel_launch(void* const* d_in, const int* in_sizes, int n_in,
                              void* d_out, int out_size, void* d_ws, size_t ws_size,
                              hipStream_t stream) {
    const float* x  = (const float*)d_in[0];
    const float* Wk = (const float*)d_in[1];
    const float* Wq = (const float*)d_in[2];
    const float* Wv = (const float*)d_in[3];
    float* out = (float*)d_out;
    uint8_t* ws = (uint8_t*)d_ws;

    // Workspace: acc (bf16-packed, 8 slices) 33,554,432 | wb 786,432 |
    //            qb/kb/vTb 3x4,194,304 | m_ws 524,288 | l_ws 524,288
    const size_t NEED = 47972352;

    if (ws_size >= NEED) {
        unsigned int* acc_ws = (unsigned int*)ws;
        __bf16* wb  = (__bf16*)(ws + 33554432);
        __bf16* qb  = (__bf16*)(ws + 34340864);
        __bf16* kb  = (__bf16*)(ws + 38535168);
        __bf16* vTb = (__bf16*)(ws + 42729472);
        float*  m_ws = (float*)(ws + 46923776);
        float*  l_ws = (float*)(ws + 47448064);

        wprep_kernel<<<384, 256, 0, stream>>>(Wq, Wk, Wv, wb);
        proj_fused<<<768, 256, 0, stream>>>(x, wb, qb, kb, vTb);
        attn_fused<<<B_ * 36, 512, 0, stream>>>(qb, kb, vTb, acc_ws, m_ws, l_ws);
        attn_merge_bal<<<M_ / 4, 256, 0, stream>>>(acc_ws, m_ws, l_ws, out);
    } else {
        // Fallback: round-4 verified path (needs 12.6 MB)
        __bf16* qb  = (__bf16*)d_ws;
        __bf16* kb  = qb + (size_t)M_ * H_;
        __bf16* vTb = kb + (size_t)M_ * H_;
        proj_kernel<<<3072, 64, 0, stream>>>(x, Wq, Wk, Wv, qb, kb, vTb);
        attn_kernel<<<1024, 64, 0, stream>>>(qb, kb, vTb, out);
    }
}